// Round 3
// baseline (2526.440 us; speedup 1.0000x reference)
//
#include <hip/hip_runtime.h>

#define NPTS 8192
#define NCH 8
#define STRIDE 6144
#define TOTAL 51200
#define FADE 1228
#define GW 0.00390625f   // 2^-8, exact cell width; C in [0,0.05) -> cells 0..12

// ---------------------------------------------------------------------------
// copy chunks[0] -> fin[0]  and  init all jmax buffers to -1
__global__ void k_setup(const float* __restrict__ chunks, float* __restrict__ fin,
                        int* __restrict__ jmax_all) {
    int i = blockIdx.x * 256 + threadIdx.x;
    if (i < NPTS * 3) fin[i] = chunks[i];
    if (i < (NCH - 1) * NPTS) jmax_all[i] = -1;
}

// ---------------------------------------------------------------------------
// Build per-chunk cell-sorted point lists (chunks 1..7). One block per chunk.
// cc computed with the exact reference chain: (x*x + y*y) + z*z.
__global__ __launch_bounds__(256) void k_gridbuild(const float* __restrict__ chunks,
        float4* __restrict__ spts, int* __restrict__ sidx, int* __restrict__ cstart_all) {
#pragma clang fp contract(off)
    __shared__ int cnt[4096];
    __shared__ int scanbuf[256];
    int tid = threadIdx.x;
    int chunk = blockIdx.x + 1;                       // 1..7
    const float* C = chunks + chunk * NPTS * 3;
    float4* sp = spts + blockIdx.x * NPTS;
    int* si = sidx + blockIdx.x * NPTS;
    int* cs = cstart_all + blockIdx.x * 4097;

    for (int i = tid; i < 4096; i += 256) cnt[i] = 0;
    __syncthreads();
    for (int k = tid; k < NPTS; k += 256) {
        float x = C[k * 3 + 0], y = C[k * 3 + 1], z = C[k * 3 + 2];
        int cx = (int)floorf(x * 256.0f), cy = (int)floorf(y * 256.0f), cz = (int)floorf(z * 256.0f);
        atomicAdd(&cnt[(cz << 8) | (cy << 4) | cx], 1);
    }
    __syncthreads();
    // exclusive scan over 4096 (16 per thread + Hillis-Steele over 256)
    int base = tid * 16, sum = 0;
    int loc[16];
#pragma unroll
    for (int t = 0; t < 16; ++t) { loc[t] = sum; sum += cnt[base + t]; }
    scanbuf[tid] = sum;
    __syncthreads();
    for (int off = 1; off < 256; off <<= 1) {
        int v = (tid >= off) ? scanbuf[tid - off] : 0;
        __syncthreads();
        scanbuf[tid] += v;
        __syncthreads();
    }
    int start0 = scanbuf[tid] - sum;                  // exclusive block offset
#pragma unroll
    for (int t = 0; t < 16; ++t) cs[base + t] = start0 + loc[t];
    if (tid == 0) cs[4096] = NPTS;
    __syncthreads();
#pragma unroll
    for (int t = 0; t < 16; ++t) cnt[base + t] = start0 + loc[t];   // cursors
    __syncthreads();
    for (int k = tid; k < NPTS; k += 256) {
        float x = C[k * 3 + 0], y = C[k * 3 + 1], z = C[k * 3 + 2];
        int cx = (int)floorf(x * 256.0f), cy = (int)floorf(y * 256.0f), cz = (int)floorf(z * 256.0f);
        int pos = atomicAdd(&cnt[(cz << 8) | (cy << 4) | cx], 1);
        float cc = (x * x + y * y) + z * z;
        sp[pos] = make_float4(x, y, z, cc);
        si[pos] = k;
    }
}

// ---------------------------------------------------------------------------
// Fused grid-NN argmin + weight-predictor MLP + fused-combine + jmax atomicMax.
// 2 lanes per query (cells split by visit-parity), block = 128 thr = 64 queries.
__global__ __launch_bounds__(128) void k_argmid(
        const float* __restrict__ P, const float* __restrict__ C,
        const float4* __restrict__ spts, const int* __restrict__ sidx,
        const int* __restrict__ cstart,
        const float* __restrict__ w1g, const float* __restrict__ b1g,
        const float* __restrict__ w2g, const float* __restrict__ b2g,
        const float* __restrict__ w3g, const float* __restrict__ b3g,
        float* __restrict__ fused, int* __restrict__ jmax) {
#pragma clang fp contract(off)
    __shared__ int cs[4097];
    __shared__ float W[780];     // w1[0:192) b1[192:224) w2[224:736) b2[736:752) w3[752:768) b3[768]
    __shared__ int dm[64], dj[64];
    int tid = threadIdx.x;
    for (int i = tid; i < 4097; i += 128) cs[i] = cstart[i];
    for (int i = tid; i < 780; i += 128) {
        float v;
        if (i < 192) v = w1g[i];
        else if (i < 224) v = b1g[i - 192];
        else if (i < 736) v = w2g[i - 224];
        else if (i < 752) v = b2g[i - 736];
        else if (i < 768) v = w3g[i - 752];
        else v = b3g[0];
        W[i] = v;
    }
    __syncthreads();

    int qid = (blockIdx.x * 128 + tid) >> 1;
    int half = tid & 1;
    float q0 = P[qid * 3 + 0], q1 = P[qid * 3 + 1], q2 = P[qid * 3 + 2];
    float pp = (q0 * q0 + q1 * q1) + q2 * q2;

    int cx = (int)floorf(q0 * 256.0f); cx = cx < 0 ? 0 : (cx > 12 ? 12 : cx);
    int cy = (int)floorf(q1 * 256.0f); cy = cy < 0 ? 0 : (cy > 12 ? 12 : cy);
    int cz = (int)floorf(q2 * 256.0f); cz = cz < 0 ? 0 : (cz > 12 ? 12 : cz);

    // max overhang over VALID directions only (invalid dirs have no cells)
    float omax = 0.0f;
    if (cx < 12) omax = fmaxf(omax, q0 - (float)(cx + 1) * GW);
    if (cx > 0)  omax = fmaxf(omax, (float)cx * GW - q0);
    if (cy < 12) omax = fmaxf(omax, q1 - (float)(cy + 1) * GW);
    if (cy > 0)  omax = fmaxf(omax, (float)cy * GW - q1);
    if (cz < 12) omax = fmaxf(omax, q2 - (float)(cz + 1) * GW);
    if (cz > 0)  omax = fmaxf(omax, (float)cz * GW - q2);

    float best = 3.4e38f;
    int bk = 0x7FFFFFFF;
    int cnt = 0;

#define VISIT(XV)                                                               \
    do {                                                                        \
        int xv = (XV);                                                          \
        if ((cnt++ & 1) == half) {                                              \
            float lx = (float)xv * GW;                                          \
            float ddx = fmaxf(fmaxf(lx - q0, q0 - (lx + GW)), 0.0f);            \
            float lb = yzpart + ddx * ddx;                                      \
            if (!(lb * 0.99999f - 1e-7f > best)) {                              \
                int cell = (z << 8) | (y << 4) | xv;                            \
                int a0 = cs[cell], e0 = cs[cell + 1];                           \
                for (int ii = a0; ii < e0; ++ii) {                              \
                    float4 pt = spts[ii];                                       \
                    int kk = sidx[ii];                                          \
                    float g = __builtin_fmaf(q2, pt.z,                          \
                              __builtin_fmaf(q1, pt.y, q0 * pt.x));             \
                    float sadd = pp + pt.w;                                     \
                    float d = __builtin_fmaf(-2.0f, g, sadd);                   \
                    if (d < best || (d == best && kk < bk)) { best = d; bk = kk; } \
                }                                                               \
            }                                                                   \
        }                                                                       \
    } while (0)

    for (int s = 0; s <= 12; ++s) {
        if (s >= 1) {
            float t = (float)(s - 1) * GW - omax;
            if (t > 0.0f && t * t * 0.99999f - 1e-7f > best) break;
        }
        int zlo = cz - s < 0 ? 0 : cz - s, zhi = cz + s > 12 ? 12 : cz + s;
        int ylo = cy - s < 0 ? 0 : cy - s, yhi = cy + s > 12 ? 12 : cy + s;
        int xlo = cx - s < 0 ? 0 : cx - s, xhi = cx + s > 12 ? 12 : cx + s;
        for (int z = zlo; z <= zhi; ++z) {
            int az = z - cz; az = az < 0 ? -az : az;
            float lz = (float)z * GW;
            float ddz = fmaxf(fmaxf(lz - q2, q2 - (lz + GW)), 0.0f);
            float zpart = ddz * ddz;
            for (int y = ylo; y <= yhi; ++y) {
                int ay = y - cy; ay = ay < 0 ? -ay : ay;
                float ly = (float)y * GW;
                float ddy = fmaxf(fmaxf(ly - q1, q1 - (ly + GW)), 0.0f);
                float yzpart = zpart + ddy * ddy;
                int amax = az > ay ? az : ay;
                if (amax == s) {
                    for (int x = xlo; x <= xhi; ++x) VISIT(x);
                } else {
                    if (cx - s >= 0)  VISIT(cx - s);
                    if (cx + s <= 12) VISIT(cx + s);
                }
            }
        }
    }
#undef VISIT

    // merge the two lanes of this query (lexicographic (d,k) min)
    {
        float od = __shfl_xor(best, 1);
        int okk = __shfl_xor(bk, 1);
        if (od < best || (od == best && okk < bk)) { best = od; bk = okk; }
    }
    int m = bk;

    // weight-predictor MLP (both lanes compute; chains identical to round 2)
    float x6[6];
    x6[0] = q0; x6[1] = q1; x6[2] = q2;
    x6[3] = C[m * 3 + 0]; x6[4] = C[m * 3 + 1]; x6[5] = C[m * 3 + 2];
    float h1[32];
#pragma unroll
    for (int o = 0; o < 32; ++o) {
        float acc = 0.0f;
#pragma unroll
        for (int ci = 0; ci < 6; ++ci) acc = __builtin_fmaf(x6[ci], W[o * 6 + ci], acc);
        h1[o] = fmaxf(acc + W[192 + o], 0.0f);
    }
    float h2[16];
#pragma unroll
    for (int o = 0; o < 16; ++o) {
        float acc = 0.0f;
#pragma unroll
        for (int ci = 0; ci < 32; ++ci) acc = __builtin_fmaf(h1[ci], W[224 + o * 32 + ci], acc);
        h2[o] = fmaxf(acc + W[736 + o], 0.0f);
    }
    float acc = 0.0f;
#pragma unroll
    for (int ci = 0; ci < 16; ++ci) acc = __builtin_fmaf(h2[ci], W[752 + ci], acc);
    float zz = acc + W[768];
    float w = 1.0f / (1.0f + expf(-zz));
    float omw = 1.0f - w;
    if (half == 0) {
#pragma unroll
        for (int e = 0; e < 3; ++e) {
            float t1 = w * x6[e];
            float t2 = omw * x6[3 + e];
            fused[e * NPTS + qid] = t1 + t2;
        }
        dm[tid >> 1] = m;
        dj[tid >> 1] = qid;
    }
    __syncthreads();
    if (half == 0) {
        bool dead = false;
        for (int t = 0; t < 64; ++t)
            if (dm[t] == m && dj[t] > qid) dead = true;
        if (!dead) atomicMax(&jmax[m], qid);
    }
}

// ---------------------------------------------------------------------------
// fused boundary smoother (verbatim from round 2 — verified bit-exact)
#define S1 41
#define S2 37
__global__ __launch_bounds__(256) void k_smoother(const float* __restrict__ fused,
        const float* __restrict__ w1g, const float* __restrict__ b1g,
        const float* __restrict__ w2g, const float* __restrict__ b2g,
        const float* __restrict__ w3g, const float* __restrict__ b3g,
        float* __restrict__ sm) {
#pragma clang fp contract(off)
    __shared__ float F[3][44];
    __shared__ float H1[32][S1];
    __shared__ float H2[32][S2];
    __shared__ float W2[5120];
    __shared__ float B2[32];
    int tid = threadIdx.x;
    int BASE = blockIdx.x * 32;

    for (int li = tid; li < 132; li += 256) {
        int c = li / 44, i = li % 44;
        int t = BASE - 6 + i;
        F[c][i] = (t >= 0 && t < NPTS) ? fused[c * NPTS + t] : 0.0f;
    }
    for (int li = tid; li < 1280; li += 256) {
        float4 v = ((const float4*)w2g)[li];
        int base = li * 4;
#pragma unroll
        for (int u = 0; u < 4; ++u) {
            int idx = base + u;
            int co = idx / 160;
            int r = idx - co * 160;
            int ci = r / 5;
            int k = r - ci * 5;
            W2[(ci * 5 + k) * 32 + co] = (&v.x)[u];
        }
    }
    if (tid < 32) B2[tid] = b2g[tid];
    __syncthreads();

    {
        int co = tid >> 3, pg = tid & 7;
        float wr[15];
#pragma unroll
        for (int q = 0; q < 15; ++q) wr[q] = w1g[co * 15 + q];
        float bias = b1g[co];
#pragma unroll
        for (int s = 0; s < 5; ++s) {
            int i = pg * 5 + s;
            int t = BASE - 4 + i;
            float acc = 0.0f;
#pragma unroll
            for (int k = 0; k < 5; ++k)
#pragma unroll
                for (int ci = 0; ci < 3; ++ci)
                    acc = __builtin_fmaf(F[ci][i + k], wr[ci * 5 + k], acc);
            H1[co][i] = (t >= 0 && t < NPTS) ? fmaxf(acc + bias, 0.0f) : 0.0f;
        }
    }
    __syncthreads();

    {
        int cq = tid & 7, pp = tid >> 3;
        if (pp < 18) {
            int i2 = pp * 2;
            int co0 = cq * 4;
            float acc00 = 0.f, acc01 = 0.f, acc02 = 0.f, acc03 = 0.f;
            float acc10 = 0.f, acc11 = 0.f, acc12 = 0.f, acc13 = 0.f;
            for (int k = 0; k < 5; ++k) {
#pragma unroll
                for (int ci = 0; ci < 32; ++ci) {
                    float in0 = H1[ci][i2 + k];
                    float in1 = H1[ci][i2 + k + 1];
                    const float4 wv = *(const float4*)&W2[(ci * 5 + k) * 32 + co0];
                    acc00 = __builtin_fmaf(in0, wv.x, acc00);
                    acc01 = __builtin_fmaf(in0, wv.y, acc01);
                    acc02 = __builtin_fmaf(in0, wv.z, acc02);
                    acc03 = __builtin_fmaf(in0, wv.w, acc03);
                    acc10 = __builtin_fmaf(in1, wv.x, acc10);
                    acc11 = __builtin_fmaf(in1, wv.y, acc11);
                    acc12 = __builtin_fmaf(in1, wv.z, acc12);
                    acc13 = __builtin_fmaf(in1, wv.w, acc13);
                }
            }
            int t0 = BASE - 2 + i2, t1 = t0 + 1;
            bool ok0 = (t0 >= 0 && t0 < NPTS), ok1 = (t1 >= 0 && t1 < NPTS);
            H2[co0 + 0][i2]     = ok0 ? fmaxf(acc00 + B2[co0 + 0], 0.0f) : 0.0f;
            H2[co0 + 1][i2]     = ok0 ? fmaxf(acc01 + B2[co0 + 1], 0.0f) : 0.0f;
            H2[co0 + 2][i2]     = ok0 ? fmaxf(acc02 + B2[co0 + 2], 0.0f) : 0.0f;
            H2[co0 + 3][i2]     = ok0 ? fmaxf(acc03 + B2[co0 + 3], 0.0f) : 0.0f;
            H2[co0 + 0][i2 + 1] = ok1 ? fmaxf(acc10 + B2[co0 + 0], 0.0f) : 0.0f;
            H2[co0 + 1][i2 + 1] = ok1 ? fmaxf(acc11 + B2[co0 + 1], 0.0f) : 0.0f;
            H2[co0 + 2][i2 + 1] = ok1 ? fmaxf(acc12 + B2[co0 + 2], 0.0f) : 0.0f;
            H2[co0 + 3][i2 + 1] = ok1 ? fmaxf(acc13 + B2[co0 + 3], 0.0f) : 0.0f;
        }
    }
    __syncthreads();

    if (tid < 96) {
        int co = tid >> 5, p = tid & 31;
        float wr[160];
        const float4* w3v = (const float4*)(w3g + co * 160);
#pragma unroll
        for (int q = 0; q < 40; ++q) {
            float4 v = w3v[q];
            wr[q * 4 + 0] = v.x; wr[q * 4 + 1] = v.y;
            wr[q * 4 + 2] = v.z; wr[q * 4 + 3] = v.w;
        }
        float acc = 0.0f;
#pragma unroll
        for (int k = 0; k < 5; ++k)
#pragma unroll
            for (int ci = 0; ci < 32; ++ci)
                acc = __builtin_fmaf(H2[ci][p + k], wr[ci * 5 + k], acc);
        sm[(BASE + p) * 3 + co] = acc + b3g[co];
    }
}

// ---------------------------------------------------------------------------
__global__ void k_scatter(const int* __restrict__ jmax, const float* __restrict__ sm,
                          const float* __restrict__ C, float* __restrict__ outPM) {
    int k = blockIdx.x * 256 + threadIdx.x;
    int jm = jmax[k];
    if (jm >= 0) {
        outPM[k * 3 + 0] = sm[jm * 3 + 0];
        outPM[k * 3 + 1] = sm[jm * 3 + 1];
        outPM[k * 3 + 2] = sm[jm * 3 + 2];
    } else {
        outPM[k * 3 + 0] = C[k * 3 + 0];
        outPM[k * 3 + 1] = C[k * 3 + 1];
        outPM[k * 3 + 2] = C[k * 3 + 2];
    }
}

// ---------------------------------------------------------------------------
__global__ void k_merge(const float* __restrict__ fin, float* __restrict__ out) {
#pragma clang fp contract(off)
    int pos = blockIdx.x * 256 + threadIdx.x;
    if (pos >= TOTAL) return;
    int imax = pos / STRIDE; if (imax > NCH - 1) imax = NCH - 1;
    int imin = (pos >= NPTS) ? ((pos - NPTS) / STRIDE + 1) : 0;
    float a0 = 0.0f, a1 = 0.0f, a2 = 0.0f, wsum = 0.0f;
    const float kstep = 0.9f / 1227.0f;
    for (int i = imin; i <= imax; ++i) {
        int t = pos - i * STRIDE;
        float cw;
        if (t < FADE)                cw = 0.1f + (float)t * kstep;
        else if (t >= NPTS - FADE)   cw = 1.0f - (float)(t - (NPTS - FADE)) * kstep;
        else                         cw = 1.0f;
        const float* v = fin + (i * NPTS + t) * 3;
        a0 += cw * v[0];
        a1 += cw * v[1];
        a2 += cw * v[2];
        wsum += cw;
    }
    float wm = fmaxf(wsum, 1e-8f);
    out[pos * 3 + 0] = a0 / wm;
    out[pos * 3 + 1] = a1 / wm;
    out[pos * 3 + 2] = a2 / wm;
}

// ---------------------------------------------------------------------------
extern "C" void kernel_launch(void* const* d_in, const int* in_sizes, int n_in,
                              void* d_out, int out_size, void* d_ws, size_t ws_size,
                              hipStream_t stream) {
    const float* chunks = (const float*)d_in[0];
    const float* bs_w1 = (const float*)d_in[1];
    const float* bs_b1 = (const float*)d_in[2];
    const float* bs_w2 = (const float*)d_in[3];
    const float* bs_b2 = (const float*)d_in[4];
    const float* bs_w3 = (const float*)d_in[5];
    const float* bs_b3 = (const float*)d_in[6];
    const float* wp_w1 = (const float*)d_in[7];
    const float* wp_b1 = (const float*)d_in[8];
    const float* wp_w2 = (const float*)d_in[9];
    const float* wp_b2 = (const float*)d_in[10];
    const float* wp_w3 = (const float*)d_in[11];
    const float* wp_b3 = (const float*)d_in[12];

    float* ws = (float*)d_ws;
    float* fin      = ws;                            // 196608 f32
    float* fused    = fin + NCH * NPTS * 3;          // 24576 f32
    float4* spts    = (float4*)(fused + 3 * NPTS);   // 7*8192 float4 = 229376 f32
    int*   sidx     = (int*)(spts + 7 * NPTS);       // 57344 i32
    int*   cstart   = sidx + 7 * NPTS;               // 7*4097 = 28679 i32
    int*   jmax_all = cstart + 7 * 4097;             // 57344 i32
    // total ~2.3 MB

    k_setup<<<224, 256, 0, stream>>>(chunks, fin, jmax_all);
    k_gridbuild<<<7, 256, 0, stream>>>(chunks, spts, sidx, cstart);

    for (int i = 1; i < NCH; ++i) {
        const float* C = chunks + i * NPTS * 3;
        float* P  = fin + (i - 1) * NPTS * 3;
        float* Pn = fin + i * NPTS * 3;
        int* jmax = jmax_all + (i - 1) * NPTS;

        k_argmid<<<128, 128, 0, stream>>>(P, C, spts + (i - 1) * NPTS,
                                          sidx + (i - 1) * NPTS, cstart + (i - 1) * 4097,
                                          wp_w1, wp_b1, wp_w2, wp_b2, wp_w3, wp_b3,
                                          fused, jmax);
        k_smoother<<<256, 256, 0, stream>>>(fused, bs_w1, bs_b1, bs_w2, bs_b2,
                                            bs_w3, bs_b3, P);
        k_scatter<<<32, 256, 0, stream>>>(jmax, P, C, Pn);
    }

    k_merge<<<200, 256, 0, stream>>>(fin, (float*)d_out);
}

// Round 4
// 396.596 us; speedup vs baseline: 6.3703x; 6.3703x over previous
//
#include <hip/hip_runtime.h>

#define NPTS 8192
#define NCH 8
#define STRIDE 6144
#define TOTAL 51200
#define FADE 1228
#define SEG 32
#define SEGLEN 256   // NPTS / SEG
#define JB 4         // j's per thread in argmin

// ---------------------------------------------------------------------------
// copy ALL chunks -> fin (chunk i pre-filled so smoother epilogue only writes
// winner rows), init jmax to -1, init packed argmin buffers to all-ones.
__global__ void k_setup(const float* __restrict__ chunks, float* __restrict__ fin,
                        int* __restrict__ jmax_all, unsigned int* __restrict__ packed32) {
    int i = blockIdx.x * 256 + threadIdx.x;            // grid covers 196608
    if (i < NCH * NPTS * 3) fin[i] = chunks[i];
    if (i < (NCH - 1) * NPTS) jmax_all[i] = -1;
    if (i < (NCH - 1) * NPTS * 2) packed32[i] = 0xFFFFFFFFu;
}

// ---------------------------------------------------------------------------
// Brute-force argmin over a 256-candidate segment, JB=4 queries per thread.
// d chain bit-identical to round 2: g = fma(p2,cz, fma(p1,cy, p0*cx));
// sadd = pp + cc; d = fma(-2, g, sadd)  [== (pp+cc) - 2g, single rounding].
// Cross-segment winner via lexicographic (d,k) atomicMin on packed u64:
// identical to ascending strict-< scan, order-independent.
__global__ __launch_bounds__(256) void k_argmin(const float* __restrict__ P,
                                                const float* __restrict__ C,
                                                unsigned long long* __restrict__ packed) {
#pragma clang fp contract(off)
    __shared__ float4 sh[SEGLEN];
    int tid = threadIdx.x;
    int k0 = blockIdx.y * SEGLEN;
    {
        int k = k0 + tid;
        float x = C[k * 3 + 0], y = C[k * 3 + 1], z = C[k * 3 + 2];
        float cc = (x * x + y * y) + z * z;
        sh[tid] = make_float4(x, y, z, cc);
    }
    __syncthreads();
    int j0 = blockIdx.x * (256 * JB) + tid * JB;
    const float4* Pv = (const float4*)(P + j0 * 3);    // 12 floats, 16B-aligned
    float4 a = Pv[0], b = Pv[1], c4 = Pv[2];
    float p0[JB] = {a.x, a.w, b.z, c4.y};
    float p1[JB] = {a.y, b.x, b.w, c4.z};
    float p2[JB] = {a.z, b.y, c4.x, c4.w};
    float pp[JB], best[JB];
    int bt[JB];
#pragma unroll
    for (int i = 0; i < JB; ++i) {
        pp[i] = (p0[i] * p0[i] + p1[i] * p1[i]) + p2[i] * p2[i];
        best[i] = 3.4e38f;
        bt[i] = 0;
    }
#pragma unroll 4
    for (int t = 0; t < SEGLEN; ++t) {
        float4 f = sh[t];
#pragma unroll
        for (int i = 0; i < JB; ++i) {
            float g = __builtin_fmaf(p2[i], f.z, __builtin_fmaf(p1[i], f.y, p0[i] * f.x));
            float sadd = pp[i] + f.w;
            float d = __builtin_fmaf(-2.0f, g, sadd);
            if (d < best[i]) { best[i] = d; bt[i] = t; }   // strict <: lowest t wins ties
        }
    }
#pragma unroll
    for (int i = 0; i < JB; ++i) {
        unsigned ud = __float_as_uint(best[i]);
        if (ud == 0x80000000u) ud = 0u;                 // canonicalize -0 -> +0 (bitwise)
        ud = (ud & 0x80000000u) ? ~ud : (ud | 0x80000000u);   // order-preserving map
        unsigned long long pk = ((unsigned long long)ud << 32)
                              | (unsigned long long)(unsigned)(k0 + bt[i]);
        atomicMin(&packed[j0 + i], pk);
    }
}

// ---------------------------------------------------------------------------
// unpack match index + weight-predictor MLP (weights in LDS) + fused-combine
// + deduped jmax atomicMax. 64 blocks x 128 threads, one query per thread.
__global__ __launch_bounds__(128) void k_resolve(
        const float* __restrict__ P, const float* __restrict__ C,
        const unsigned long long* __restrict__ packed,
        const float* __restrict__ w1g, const float* __restrict__ b1g,
        const float* __restrict__ w2g, const float* __restrict__ b2g,
        const float* __restrict__ w3g, const float* __restrict__ b3g,
        float* __restrict__ fused, int* __restrict__ mi, int* __restrict__ jmax) {
#pragma clang fp contract(off)
    __shared__ float W[780];   // w1[0:192) b1[192:224) w2[224:736) b2[736:752) w3[752:768) b3[768]
    int tid = threadIdx.x;
    for (int i = tid; i < 780; i += 128) {
        float v;
        if (i < 192) v = w1g[i];
        else if (i < 224) v = b1g[i - 192];
        else if (i < 736) v = w2g[i - 224];
        else if (i < 752) v = b2g[i - 736];
        else if (i < 768) v = w3g[i - 752];
        else v = b3g[0];
        W[i] = v;
    }
    __syncthreads();

    int j = blockIdx.x * 128 + tid;
    int m = (int)(unsigned)(packed[j] & 0xFFFFFFFFull);
    mi[j] = m;
    float x6[6];
    x6[0] = P[j * 3 + 0]; x6[1] = P[j * 3 + 1]; x6[2] = P[j * 3 + 2];
    x6[3] = C[m * 3 + 0]; x6[4] = C[m * 3 + 1]; x6[5] = C[m * 3 + 2];

    float h1[32];
#pragma unroll
    for (int o = 0; o < 32; ++o) {
        float acc = 0.0f;
#pragma unroll
        for (int ci = 0; ci < 6; ++ci) acc = __builtin_fmaf(x6[ci], W[o * 6 + ci], acc);
        h1[o] = fmaxf(acc + W[192 + o], 0.0f);
    }
    float h2[16];
#pragma unroll
    for (int o = 0; o < 16; ++o) {
        float acc = 0.0f;
#pragma unroll
        for (int ci = 0; ci < 32; ++ci) acc = __builtin_fmaf(h1[ci], W[224 + o * 32 + ci], acc);
        h2[o] = fmaxf(acc + W[736 + o], 0.0f);
    }
    float acc = 0.0f;
#pragma unroll
    for (int ci = 0; ci < 16; ++ci) acc = __builtin_fmaf(h2[ci], W[752 + ci], acc);
    float z = acc + W[768];
    float w = 1.0f / (1.0f + expf(-z));
    float omw = 1.0f - w;
#pragma unroll
    for (int e = 0; e < 3; ++e) {
        float t1 = w * x6[e];
        float t2 = omw * x6[3 + e];
        fused[e * NPTS + j] = t1 + t2;
    }

    // wave-level dedupe: only the highest-j lane per distinct m issues the atomic
    int lane = tid & 63;
    bool issue = true;
    for (int s = 1; s < 64; ++s) {
        int om = __shfl_down(m, s);
        if (lane + s < 64 && om == m) issue = false;
    }
    if (issue) atomicMax(&jmax[m], j);
}

// ---------------------------------------------------------------------------
// fused boundary smoother (round-2 verified body) + fused scatter epilogue:
// winners write fin_next[k] directly (fin_next pre-filled with raw chunk).
#define S1 41
#define S2 37
__global__ __launch_bounds__(256) void k_smoother(const float* __restrict__ fused,
        const float* __restrict__ w1g, const float* __restrict__ b1g,
        const float* __restrict__ w2g, const float* __restrict__ b2g,
        const float* __restrict__ w3g, const float* __restrict__ b3g,
        float* __restrict__ sm, const int* __restrict__ mi,
        const int* __restrict__ jmax, float* __restrict__ finNext) {
#pragma clang fp contract(off)
    __shared__ float F[3][44];
    __shared__ float H1[32][S1];
    __shared__ float H2[32][S2];
    __shared__ float W2[5120];
    __shared__ float B2[32];
    int tid = threadIdx.x;
    int BASE = blockIdx.x * 32;

    for (int li = tid; li < 132; li += 256) {
        int c = li / 44, i = li % 44;
        int t = BASE - 6 + i;
        F[c][i] = (t >= 0 && t < NPTS) ? fused[c * NPTS + t] : 0.0f;
    }
    for (int li = tid; li < 1280; li += 256) {
        float4 v = ((const float4*)w2g)[li];
        int base = li * 4;
#pragma unroll
        for (int u = 0; u < 4; ++u) {
            int idx = base + u;
            int co = idx / 160;
            int r = idx - co * 160;
            int ci = r / 5;
            int k = r - ci * 5;
            W2[(ci * 5 + k) * 32 + co] = (&v.x)[u];
        }
    }
    if (tid < 32) B2[tid] = b2g[tid];
    __syncthreads();

    {
        int co = tid >> 3, pg = tid & 7;
        float wr[15];
#pragma unroll
        for (int q = 0; q < 15; ++q) wr[q] = w1g[co * 15 + q];
        float bias = b1g[co];
#pragma unroll
        for (int s = 0; s < 5; ++s) {
            int i = pg * 5 + s;
            int t = BASE - 4 + i;
            float acc = 0.0f;
#pragma unroll
            for (int k = 0; k < 5; ++k)
#pragma unroll
                for (int ci = 0; ci < 3; ++ci)
                    acc = __builtin_fmaf(F[ci][i + k], wr[ci * 5 + k], acc);
            H1[co][i] = (t >= 0 && t < NPTS) ? fmaxf(acc + bias, 0.0f) : 0.0f;
        }
    }
    __syncthreads();

    {
        int cq = tid & 7, pp = tid >> 3;
        if (pp < 18) {
            int i2 = pp * 2;
            int co0 = cq * 4;
            float acc00 = 0.f, acc01 = 0.f, acc02 = 0.f, acc03 = 0.f;
            float acc10 = 0.f, acc11 = 0.f, acc12 = 0.f, acc13 = 0.f;
            for (int k = 0; k < 5; ++k) {
#pragma unroll
                for (int ci = 0; ci < 32; ++ci) {
                    float in0 = H1[ci][i2 + k];
                    float in1 = H1[ci][i2 + k + 1];
                    const float4 wv = *(const float4*)&W2[(ci * 5 + k) * 32 + co0];
                    acc00 = __builtin_fmaf(in0, wv.x, acc00);
                    acc01 = __builtin_fmaf(in0, wv.y, acc01);
                    acc02 = __builtin_fmaf(in0, wv.z, acc02);
                    acc03 = __builtin_fmaf(in0, wv.w, acc03);
                    acc10 = __builtin_fmaf(in1, wv.x, acc10);
                    acc11 = __builtin_fmaf(in1, wv.y, acc11);
                    acc12 = __builtin_fmaf(in1, wv.z, acc12);
                    acc13 = __builtin_fmaf(in1, wv.w, acc13);
                }
            }
            int t0 = BASE - 2 + i2, t1 = t0 + 1;
            bool ok0 = (t0 >= 0 && t0 < NPTS), ok1 = (t1 >= 0 && t1 < NPTS);
            H2[co0 + 0][i2]     = ok0 ? fmaxf(acc00 + B2[co0 + 0], 0.0f) : 0.0f;
            H2[co0 + 1][i2]     = ok0 ? fmaxf(acc01 + B2[co0 + 1], 0.0f) : 0.0f;
            H2[co0 + 2][i2]     = ok0 ? fmaxf(acc02 + B2[co0 + 2], 0.0f) : 0.0f;
            H2[co0 + 3][i2]     = ok0 ? fmaxf(acc03 + B2[co0 + 3], 0.0f) : 0.0f;
            H2[co0 + 0][i2 + 1] = ok1 ? fmaxf(acc10 + B2[co0 + 0], 0.0f) : 0.0f;
            H2[co0 + 1][i2 + 1] = ok1 ? fmaxf(acc11 + B2[co0 + 1], 0.0f) : 0.0f;
            H2[co0 + 2][i2 + 1] = ok1 ? fmaxf(acc12 + B2[co0 + 2], 0.0f) : 0.0f;
            H2[co0 + 3][i2 + 1] = ok1 ? fmaxf(acc13 + B2[co0 + 3], 0.0f) : 0.0f;
        }
    }
    __syncthreads();

    if (tid < 96) {
        int co = tid >> 5, p = tid & 31;
        float wr[160];
        const float4* w3v = (const float4*)(w3g + co * 160);
#pragma unroll
        for (int q = 0; q < 40; ++q) {
            float4 v = w3v[q];
            wr[q * 4 + 0] = v.x; wr[q * 4 + 1] = v.y;
            wr[q * 4 + 2] = v.z; wr[q * 4 + 3] = v.w;
        }
        float acc = 0.0f;
#pragma unroll
        for (int k = 0; k < 5; ++k)
#pragma unroll
            for (int ci = 0; ci < 32; ++ci)
                acc = __builtin_fmaf(H2[ci][p + k], wr[ci * 5 + k], acc);
        float val = acc + b3g[co];
        int jj = BASE + p;
        sm[jj * 3 + co] = val;
        // fused scatter: unique winner j per k (jmax finalized in k_resolve)
        int kk = mi[jj];
        if (jmax[kk] == jj) finNext[kk * 3 + co] = val;
    }
}

// ---------------------------------------------------------------------------
__global__ void k_merge(const float* __restrict__ fin, float* __restrict__ out) {
#pragma clang fp contract(off)
    int pos = blockIdx.x * 256 + threadIdx.x;
    if (pos >= TOTAL) return;
    int imax = pos / STRIDE; if (imax > NCH - 1) imax = NCH - 1;
    int imin = (pos >= NPTS) ? ((pos - NPTS) / STRIDE + 1) : 0;
    float a0 = 0.0f, a1 = 0.0f, a2 = 0.0f, wsum = 0.0f;
    const float kstep = 0.9f / 1227.0f;
    for (int i = imin; i <= imax; ++i) {
        int t = pos - i * STRIDE;
        float cw;
        if (t < FADE)                cw = 0.1f + (float)t * kstep;
        else if (t >= NPTS - FADE)   cw = 1.0f - (float)(t - (NPTS - FADE)) * kstep;
        else                         cw = 1.0f;
        const float* v = fin + (i * NPTS + t) * 3;
        a0 += cw * v[0];
        a1 += cw * v[1];
        a2 += cw * v[2];
        wsum += cw;
    }
    float wm = fmaxf(wsum, 1e-8f);
    out[pos * 3 + 0] = a0 / wm;
    out[pos * 3 + 1] = a1 / wm;
    out[pos * 3 + 2] = a2 / wm;
}

// ---------------------------------------------------------------------------
extern "C" void kernel_launch(void* const* d_in, const int* in_sizes, int n_in,
                              void* d_out, int out_size, void* d_ws, size_t ws_size,
                              hipStream_t stream) {
    const float* chunks = (const float*)d_in[0];
    const float* bs_w1 = (const float*)d_in[1];
    const float* bs_b1 = (const float*)d_in[2];
    const float* bs_w2 = (const float*)d_in[3];
    const float* bs_b2 = (const float*)d_in[4];
    const float* bs_w3 = (const float*)d_in[5];
    const float* bs_b3 = (const float*)d_in[6];
    const float* wp_w1 = (const float*)d_in[7];
    const float* wp_b1 = (const float*)d_in[8];
    const float* wp_w2 = (const float*)d_in[9];
    const float* wp_b2 = (const float*)d_in[10];
    const float* wp_w3 = (const float*)d_in[11];
    const float* wp_b3 = (const float*)d_in[12];

    unsigned long long* packed_all = (unsigned long long*)d_ws;   // 7*8192 u64 (8B-aligned base)
    float* fin      = (float*)(packed_all + (NCH - 1) * NPTS);    // 196608 f32
    float* fused    = fin + NCH * NPTS * 3;                       // 24576 f32
    int*   mi       = (int*)(fused + 3 * NPTS);                   // 8192 i32
    int*   jmax_all = mi + NPTS;                                  // 57344 i32
    // total ~1.6 MB

    k_setup<<<768, 256, 0, stream>>>(chunks, fin, jmax_all, (unsigned int*)packed_all);

    for (int i = 1; i < NCH; ++i) {
        const float* C = chunks + i * NPTS * 3;
        float* P  = fin + (i - 1) * NPTS * 3;
        float* Pn = fin + i * NPTS * 3;
        unsigned long long* packed = packed_all + (i - 1) * NPTS;
        int* jmax = jmax_all + (i - 1) * NPTS;

        k_argmin<<<dim3(NPTS / (256 * JB), SEG), 256, 0, stream>>>(P, C, packed);
        k_resolve<<<64, 128, 0, stream>>>(P, C, packed, wp_w1, wp_b1, wp_w2, wp_b2,
                                          wp_w3, wp_b3, fused, mi, jmax);
        k_smoother<<<256, 256, 0, stream>>>(fused, bs_w1, bs_b1, bs_w2, bs_b2,
                                            bs_w3, bs_b3, P, mi, jmax, Pn);
    }

    k_merge<<<200, 256, 0, stream>>>(fin, (float*)d_out);
}